// Round 1
// baseline (726.640 us; speedup 1.0000x reference)
//
#include <hip/hip_runtime.h>
#include <math.h>

#define N_NODES 100000
#define N_EDGES 3200000
#define DIM 16
#define NSZ (N_NODES * DIM)   // elements per [N, DIM] output block

// Edge kernel: one thread per (edge, 4-dim chunk). 3.2M edges * 4 = 12.8M threads.
// Gathers state[row], state[col] as float4 (state = 6.4MB, L2/L3 resident),
// computes sin(xr - xc) * w, atomicAdd into agg[col].
__global__ __launch_bounds__(256)
void edge_kernel(const float* __restrict__ state,
                 const int* __restrict__ row,
                 const int* __restrict__ col,
                 const float* __restrict__ w,
                 float* __restrict__ agg) {
    int idx = blockIdx.x * blockDim.x + threadIdx.x;
    if (idx >= N_EDGES * 4) return;
    int e = idx >> 2;       // edge id
    int q = idx & 3;        // which float4 of the 16-dim row
    int r = row[e];
    int c = col[e];
    float we = w[e];
    const float4 xr = ((const float4*)state)[r * 4 + q];
    const float4 xc = ((const float4*)state)[c * 4 + q];
    float4 s;
    s.x = sinf(xr.x - xc.x) * we;
    s.y = sinf(xr.y - xc.y) * we;
    s.z = sinf(xr.z - xc.z) * we;
    s.w = sinf(xr.w - xc.w) * we;
    float* dst = agg + c * DIM + q * 4;
    atomicAdd(dst + 0, s.x);
    atomicAdd(dst + 1, s.y);
    atomicAdd(dst + 2, s.z);
    atomicAdd(dst + 3, s.w);
}

// Node kernel: one thread per (node, 4-dim chunk). Writes out0/out1/out2/out4;
// out3 (agg) was accumulated in place by edge_kernel.
__global__ __launch_bounds__(256)
void node_kernel(const float* __restrict__ state,
                 const float* __restrict__ agg,
                 float* __restrict__ out) {
    int idx = blockIdx.x * blockDim.x + threadIdx.x;
    if (idx >= N_NODES * 4) return;
    float4 x = ((const float4*)state)[idx];
    float4 a = ((const float4*)agg)[idx];
    float4 t;
    t.x = tanhf(a.x);
    t.y = tanhf(a.y);
    t.z = tanhf(a.z);
    t.w = tanhf(a.w);
    float4 o0 = make_float4(t.x - x.x, t.y - x.y, t.z - x.z, t.w - x.w);
    float4 nx = make_float4(-x.x, -x.y, -x.z, -x.w);
    ((float4*)(out + 0 * NSZ))[idx] = o0;  // self_diff + interact_diff
    ((float4*)(out + 1 * NSZ))[idx] = x;   // state_input
    ((float4*)(out + 2 * NSZ))[idx] = nx;  // self_diff
    // out + 3*NSZ is agg, already written
    ((float4*)(out + 4 * NSZ))[idx] = t;   // interact_diff
}

extern "C" void kernel_launch(void* const* d_in, const int* in_sizes, int n_in,
                              void* d_out, int out_size, void* d_ws, size_t ws_size,
                              hipStream_t stream) {
    const float* state = (const float*)d_in[0];
    const int*   row   = (const int*)d_in[1];
    const int*   col   = (const int*)d_in[2];
    const float* w     = (const float*)d_in[3];
    float* out = (float*)d_out;
    float* agg = out + 3 * NSZ;   // out3 region doubles as the accumulator

    // Harness poisons d_out with 0xAA before every launch — zero the accumulator.
    hipMemsetAsync(agg, 0, NSZ * sizeof(float), stream);

    int edge_threads = N_EDGES * 4;
    edge_kernel<<<(edge_threads + 255) / 256, 256, 0, stream>>>(state, row, col, w, agg);

    int node_threads = N_NODES * 4;
    node_kernel<<<(node_threads + 255) / 256, 256, 0, stream>>>(state, agg, out);
}

// Round 2
// 449.175 us; speedup vs baseline: 1.6177x; 1.6177x over previous
//
#include <hip/hip_runtime.h>
#include <math.h>

#define N_NODES 100000
#define N_EDGES 3200000
#define DIM 16
#define NSZ (N_NODES * DIM)

#define SCAN_BLOCK 1024
#define NB ((N_NODES + SCAN_BLOCK - 1) / SCAN_BLOCK)   // 98

// ---------------- counting-sort path (no float atomics) ----------------

// 1) histogram of col
__global__ __launch_bounds__(256)
void hist_kernel(const int* __restrict__ col, int* __restrict__ hist) {
    int e = blockIdx.x * blockDim.x + threadIdx.x;
    if (e < N_EDGES) atomicAdd(&hist[col[e]], 1);
}

// 2a) per-block inclusive scan of hist -> off[i+1]; block totals -> bsum
__global__ __launch_bounds__(SCAN_BLOCK)
void scan_local(const int* __restrict__ hist, int* __restrict__ off,
                int* __restrict__ bsum) {
    __shared__ int s[SCAN_BLOCK];
    int t = threadIdx.x;
    int i = blockIdx.x * SCAN_BLOCK + t;
    int v = (i < N_NODES) ? hist[i] : 0;
    s[t] = v;
    __syncthreads();
    for (int d = 1; d < SCAN_BLOCK; d <<= 1) {
        int u = (t >= d) ? s[t - d] : 0;
        __syncthreads();
        s[t] += u;
        __syncthreads();
    }
    if (i < N_NODES) off[i + 1] = s[t];
    if (t == SCAN_BLOCK - 1) bsum[blockIdx.x] = s[t];
    if (i == 0) off[0] = 0;
}

// 2b) exclusive scan of the (98) block sums — single block
__global__ __launch_bounds__(128)
void scan_bsum(int* __restrict__ bsum) {
    __shared__ int s[128];
    int t = threadIdx.x;
    int v = (t < NB) ? bsum[t] : 0;
    s[t] = v;
    __syncthreads();
    for (int d = 1; d < 128; d <<= 1) {
        int u = (t >= d) ? s[t - d] : 0;
        __syncthreads();
        s[t] += u;
        __syncthreads();
    }
    if (t < NB) bsum[t] = s[t] - v;   // inclusive -> exclusive
}

// 2c) add scanned block offsets
__global__ __launch_bounds__(SCAN_BLOCK)
void scan_add(int* __restrict__ off, const int* __restrict__ bsum) {
    int i = blockIdx.x * SCAN_BLOCK + threadIdx.x;
    if (blockIdx.x > 0 && i < N_NODES) off[i + 1] += bsum[blockIdx.x];
}

// 3) scatter (row, w) into col-sorted order
__global__ __launch_bounds__(256)
void scatter_kernel(const int* __restrict__ row, const int* __restrict__ col,
                    const float* __restrict__ w, const int* __restrict__ off,
                    int* __restrict__ cursor, int2* __restrict__ sorted) {
    int e = blockIdx.x * blockDim.x + threadIdx.x;
    if (e >= N_EDGES) return;
    int c = col[e];
    int pos = off[c] + atomicAdd(&cursor[c], 1);
    sorted[pos] = make_int2(row[e], __float_as_int(w[e]));
}

// 4) per-(node, float4-chunk) gather + sin + reduce + all 5 outputs
__global__ __launch_bounds__(256)
void gather_kernel(const float* __restrict__ state, const int* __restrict__ off,
                   const int2* __restrict__ sorted, float* __restrict__ out) {
    int idx = blockIdx.x * blockDim.x + threadIdx.x;
    if (idx >= N_NODES * 4) return;
    int n = idx >> 2;
    int q = idx & 3;
    float4 xc = ((const float4*)state)[n * 4 + q];   // this node's own state chunk
    int beg = off[n], end = off[n + 1];
    float4 acc = make_float4(0.f, 0.f, 0.f, 0.f);
    for (int e = beg; e < end; ++e) {
        int2 rw = sorted[e];
        float we = __int_as_float(rw.y);
        float4 xr = ((const float4*)state)[rw.x * 4 + q];
        acc.x += sinf(xr.x - xc.x) * we;
        acc.y += sinf(xr.y - xc.y) * we;
        acc.z += sinf(xr.z - xc.z) * we;
        acc.w += sinf(xr.w - xc.w) * we;
    }
    float4 t = make_float4(tanhf(acc.x), tanhf(acc.y), tanhf(acc.z), tanhf(acc.w));
    ((float4*)(out + 0 * NSZ))[idx] = make_float4(t.x - xc.x, t.y - xc.y,
                                                  t.z - xc.z, t.w - xc.w);
    ((float4*)(out + 1 * NSZ))[idx] = xc;
    ((float4*)(out + 2 * NSZ))[idx] = make_float4(-xc.x, -xc.y, -xc.z, -xc.w);
    ((float4*)(out + 3 * NSZ))[idx] = acc;
    ((float4*)(out + 4 * NSZ))[idx] = t;
}

// ---------------- fallback: round-1 atomic path ----------------

__global__ __launch_bounds__(256)
void edge_kernel(const float* __restrict__ state, const int* __restrict__ row,
                 const int* __restrict__ col, const float* __restrict__ w,
                 float* __restrict__ agg) {
    int idx = blockIdx.x * blockDim.x + threadIdx.x;
    if (idx >= N_EDGES * 4) return;
    int e = idx >> 2;
    int q = idx & 3;
    int r = row[e], c = col[e];
    float we = w[e];
    const float4 xr = ((const float4*)state)[r * 4 + q];
    const float4 xc = ((const float4*)state)[c * 4 + q];
    float* dst = agg + c * DIM + q * 4;
    atomicAdd(dst + 0, sinf(xr.x - xc.x) * we);
    atomicAdd(dst + 1, sinf(xr.y - xc.y) * we);
    atomicAdd(dst + 2, sinf(xr.z - xc.z) * we);
    atomicAdd(dst + 3, sinf(xr.w - xc.w) * we);
}

__global__ __launch_bounds__(256)
void node_kernel(const float* __restrict__ state, const float* __restrict__ agg,
                 float* __restrict__ out) {
    int idx = blockIdx.x * blockDim.x + threadIdx.x;
    if (idx >= N_NODES * 4) return;
    float4 x = ((const float4*)state)[idx];
    float4 a = ((const float4*)agg)[idx];
    float4 t = make_float4(tanhf(a.x), tanhf(a.y), tanhf(a.z), tanhf(a.w));
    ((float4*)(out + 0 * NSZ))[idx] = make_float4(t.x - x.x, t.y - x.y,
                                                  t.z - x.z, t.w - x.w);
    ((float4*)(out + 1 * NSZ))[idx] = x;
    ((float4*)(out + 2 * NSZ))[idx] = make_float4(-x.x, -x.y, -x.z, -x.w);
    ((float4*)(out + 4 * NSZ))[idx] = t;
}

extern "C" void kernel_launch(void* const* d_in, const int* in_sizes, int n_in,
                              void* d_out, int out_size, void* d_ws, size_t ws_size,
                              hipStream_t stream) {
    const float* state = (const float*)d_in[0];
    const int*   row   = (const int*)d_in[1];
    const int*   col   = (const int*)d_in[2];
    const float* w     = (const float*)d_in[3];
    float* out = (float*)d_out;

    // workspace layout
    size_t ints_head = (size_t)(N_NODES + 1) + N_NODES + N_NODES + NB;
    size_t sorted_off = (ints_head * 4 + 15) & ~(size_t)15;       // 16B align
    size_t needed = sorted_off + (size_t)N_EDGES * 8;

    if (ws_size >= needed) {
        int* off    = (int*)d_ws;                  // N+1
        int* hist   = off + (N_NODES + 1);         // N
        int* cursor = hist + N_NODES;              // N
        int* bsum   = cursor + N_NODES;            // NB
        int2* sorted = (int2*)((char*)d_ws + sorted_off);

        // zero hist + cursor (poisoned 0xAA by harness)
        hipMemsetAsync(hist, 0, (size_t)2 * N_NODES * sizeof(int), stream);

        hist_kernel<<<(N_EDGES + 255) / 256, 256, 0, stream>>>(col, hist);
        scan_local<<<NB, SCAN_BLOCK, 0, stream>>>(hist, off, bsum);
        scan_bsum<<<1, 128, 0, stream>>>(bsum);
        scan_add<<<NB, SCAN_BLOCK, 0, stream>>>(off, bsum);
        scatter_kernel<<<(N_EDGES + 255) / 256, 256, 0, stream>>>(row, col, w, off,
                                                                  cursor, sorted);
        gather_kernel<<<(N_NODES * 4 + 255) / 256, 256, 0, stream>>>(state, off,
                                                                     sorted, out);
    } else {
        // fallback: atomic scatter path
        float* agg = out + 3 * NSZ;
        hipMemsetAsync(agg, 0, NSZ * sizeof(float), stream);
        edge_kernel<<<(N_EDGES * 4 + 255) / 256, 256, 0, stream>>>(state, row, col,
                                                                   w, agg);
        node_kernel<<<(N_NODES * 4 + 255) / 256, 256, 0, stream>>>(state, agg, out);
    }
}